// Round 3
// baseline (113.161 us; speedup 1.0000x reference)
//
#include <hip/hip_runtime.h>
#include <stdint.h>

// Problem constants
#define M_ROWS   16000        // B*T
#define N_RT     1000         // real 16-row tiles (16000/16 exactly)
#define N_RT_PAD 1008         // padded to 63 row-blocks of 16 tiles
#define D_IN     320
#define E_DIM    16
#define K_CB     8192
#define NKT      512          // 8192/16 k-tiles
#define NCHUNK   32           // k-chunks (16 k-tiles each)
#define KT_PER_CHUNK 16

typedef __attribute__((ext_vector_type(8))) short bf16x8;
typedef __attribute__((ext_vector_type(4))) float f32x4;

// Workspace layout (bytes)
#define XA_OFF   0u                       // [1008 tiles][64 lanes][8 bf16]  (h|m)
#define XB_OFF   1032192u                 // same shape                       (l|h)
#define CBA_OFF  2064384u                 // [512 ktiles][64 lanes][8 bf16]  (h'|m')
#define CBC_OFF  2588672u                 // same                             (h'|l')
#define KEYS_OFF 3112960u                 // [16128] u64

__device__ __forceinline__ unsigned short f2bf(float x) {
    union { float f; unsigned u; } v; v.f = x;
    unsigned r = v.u + 0x7FFFu + ((v.u >> 16) & 1u);   // round-to-nearest-even
    return (unsigned short)(r >> 16);
}
__device__ __forceinline__ float bf2f(unsigned short b) {
    union { unsigned u; float f; } v; v.u = ((unsigned)b) << 16; return v.f;
}

// ---------- Projection + exact 3-way bf16 split + A-fragment packing ----------
// (unchanged from round 2 — keeps X bitwise identical)
__global__ __launch_bounds__(256) void proj_pack(const float* __restrict__ hs,
                                                 const float* __restrict__ P,
                                                 unsigned short* __restrict__ Xa,
                                                 unsigned short* __restrict__ Xb) {
    int t   = threadIdx.x;
    int row = blockIdx.x * 64 + (t >> 2);
    int eq  = t & 3;
    if (row >= M_ROWS) return;
    const float* hrow = hs + (size_t)row * D_IN;
    float ax = 0.f, ay = 0.f, az = 0.f, aw = 0.f;
    #pragma unroll 4
    for (int d = 0; d < D_IN; d += 4) {
        float4 h4 = *reinterpret_cast<const float4*>(hrow + d);
        float4 p0 = *reinterpret_cast<const float4*>(P + (size_t)(d + 0) * E_DIM + eq * 4);
        float4 p1 = *reinterpret_cast<const float4*>(P + (size_t)(d + 1) * E_DIM + eq * 4);
        float4 p2 = *reinterpret_cast<const float4*>(P + (size_t)(d + 2) * E_DIM + eq * 4);
        float4 p3 = *reinterpret_cast<const float4*>(P + (size_t)(d + 3) * E_DIM + eq * 4);
        ax += h4.x * p0.x + h4.y * p1.x + h4.z * p2.x + h4.w * p3.x;
        ay += h4.x * p0.y + h4.y * p1.y + h4.z * p2.y + h4.w * p3.y;
        az += h4.x * p0.z + h4.y * p1.z + h4.z * p2.z + h4.w * p3.z;
        aw += h4.x * p0.w + h4.y * p1.w + h4.z * p2.w + h4.w * p3.w;
    }
    float v[4] = {ax, ay, az, aw};
    ushort4 h, m, l;
    unsigned short* hp = (unsigned short*)&h;
    unsigned short* mp = (unsigned short*)&m;
    unsigned short* lp = (unsigned short*)&l;
    #pragma unroll
    for (int i = 0; i < 4; ++i) {
        unsigned short hb = f2bf(v[i]);      float r1 = v[i] - bf2f(hb);
        unsigned short mb = f2bf(r1);        float r2 = r1 - bf2f(mb);
        unsigned short lb = f2bf(r2);        // exact: v = h + m + l
        hp[i] = hb; mp[i] = mb; lp[i] = lb;
    }
    int rt = row >> 4, rl = row & 15;
    int g  = eq >> 1;
    int j0 = (eq & 1) * 4;
    size_t base = (size_t)rt * 512;
    *reinterpret_cast<ushort4*>(Xa + base + ((g    ) * 16 + rl) * 8 + j0) = h;
    *reinterpret_cast<ushort4*>(Xa + base + ((2 + g) * 16 + rl) * 8 + j0) = m;
    *reinterpret_cast<ushort4*>(Xb + base + ((g    ) * 16 + rl) * 8 + j0) = l;
    *reinterpret_cast<ushort4*>(Xb + base + ((2 + g) * 16 + rl) * 8 + j0) = h;
}

// ---------- Codebook split + B-fragment packing (unchanged) ----------
__global__ __launch_bounds__(256) void cb_pack(const float* __restrict__ CB,
                                               unsigned short* __restrict__ CBa,
                                               unsigned short* __restrict__ CBc) {
    int t  = threadIdx.x;
    int c  = blockIdx.x * 64 + (t >> 2);
    int eq = t & 3;
    float4 v4 = *reinterpret_cast<const float4*>(CB + (size_t)c * E_DIM + eq * 4);
    float v[4] = {v4.x, v4.y, v4.z, v4.w};
    ushort4 h, m, l;
    unsigned short* hp = (unsigned short*)&h;
    unsigned short* mp = (unsigned short*)&m;
    unsigned short* lp = (unsigned short*)&l;
    #pragma unroll
    for (int i = 0; i < 4; ++i) {
        unsigned short hb = f2bf(v[i]);      float r1 = v[i] - bf2f(hb);
        unsigned short mb = f2bf(r1);        float r2 = r1 - bf2f(mb);
        unsigned short lb = f2bf(r2);
        hp[i] = hb; mp[i] = mb; lp[i] = lb;
    }
    int kt = c >> 4, cl = c & 15;
    int g  = eq >> 1;
    int j0 = (eq & 1) * 4;
    size_t base = (size_t)kt * 512;
    *reinterpret_cast<ushort4*>(CBa + base + ((g    ) * 16 + cl) * 8 + j0) = h;
    *reinterpret_cast<ushort4*>(CBa + base + ((2 + g) * 16 + cl) * 8 + j0) = m;
    *reinterpret_cast<ushort4*>(CBc + base + ((g    ) * 16 + cl) * 8 + j0) = h;
    *reinterpret_cast<ushort4*>(CBc + base + ((2 + g) * 16 + cl) * 8 + j0) = l;
}

__global__ __launch_bounds__(256) void init_keys(unsigned long long* __restrict__ keys) {
    int i = blockIdx.x * 256 + threadIdx.x;
    if (i < 16 * N_RT_PAD) keys[i] = 0ull;
}

// ---------- MFMA score + fused argmax, LDS-staged B ----------
// grid (63 row-blocks, 32 k-chunks) x 256 threads (4 waves).
// Block stages its whole k-chunk's CBa+CBc fragments (16KB+16KB) in LDS once;
// inner loop is pure ds_read_b128 + MFMA + argmax. The [m'|h'] operand is the
// [h'|m'] fragment read at lane^32 (second LDS read, no global stream).
__global__ __launch_bounds__(256) void score_kernel(const unsigned short* __restrict__ Xa,
                                                    const unsigned short* __restrict__ Xb,
                                                    const unsigned short* __restrict__ CBa,
                                                    const unsigned short* __restrict__ CBc,
                                                    unsigned long long* __restrict__ keys) {
    __shared__ unsigned short sA[KT_PER_CHUNK * 64 * 8];   // 16 KB  (h'|m')
    __shared__ unsigned short sC[KT_PER_CHUNK * 64 * 8];   // 16 KB  (h'|l')

    int t    = threadIdx.x;
    int lane = t & 63;
    int w    = t >> 6;
    int rb   = blockIdx.x;    // 0..62
    int kc   = blockIdx.y;    // 0..31
    int rt0  = rb * 16 + w * 4;

    // Stage B fragments for this k-chunk into LDS (float4 copies, 4 rounds each).
    {
        const float4* ga = reinterpret_cast<const float4*>(CBa + (size_t)kc * KT_PER_CHUNK * 512);
        const float4* gc = reinterpret_cast<const float4*>(CBc + (size_t)kc * KT_PER_CHUNK * 512);
        float4* la = reinterpret_cast<float4*>(sA);
        float4* lc = reinterpret_cast<float4*>(sC);
        #pragma unroll
        for (int q = 0; q < 4; ++q) la[q * 256 + t] = ga[q * 256 + t];
        #pragma unroll
        for (int q = 0; q < 4; ++q) lc[q * 256 + t] = gc[q * 256 + t];
    }

    // Load this wave's A fragments (4 row-tiles).
    bf16x8 a_hm[4], a_lh[4];
    #pragma unroll
    for (int r = 0; r < 4; ++r) {
        a_hm[r] = *reinterpret_cast<const bf16x8*>(Xa + ((size_t)(rt0 + r) * 64 + lane) * 8);
        a_lh[r] = *reinterpret_cast<const bf16x8*>(Xb + ((size_t)(rt0 + r) * 64 + lane) * 8);
    }
    float best[4][4];
    int   bidx[4][4];
    #pragma unroll
    for (int r = 0; r < 4; ++r)
        #pragma unroll
        for (int i = 0; i < 4; ++i) { best[r][i] = -3.0e38f; bidx[r][i] = 0; }

    __syncthreads();

    const bf16x8* sA8 = reinterpret_cast<const bf16x8*>(sA);
    const bf16x8* sC8 = reinterpret_cast<const bf16x8*>(sC);
    int lsw = lane ^ 32;

    #pragma unroll
    for (int kt = 0; kt < KT_PER_CHUNK; ++kt) {
        bf16x8 b1 = sA8[kt * 64 + lane];
        bf16x8 b2 = sA8[kt * 64 + lsw];
        bf16x8 b3 = sC8[kt * 64 + lane];
        #pragma unroll
        for (int r = 0; r < 4; ++r) {
            f32x4 acc = {0.f, 0.f, 0.f, 0.f};
            acc = __builtin_amdgcn_mfma_f32_16x16x32_bf16(a_hm[r], b1, acc, 0, 0, 0); // hh+mm
            acc = __builtin_amdgcn_mfma_f32_16x16x32_bf16(a_hm[r], b2, acc, 0, 0, 0); // hm+mh
            acc = __builtin_amdgcn_mfma_f32_16x16x32_bf16(a_lh[r], b3, acc, 0, 0, 0); // lh+hl
            #pragma unroll
            for (int i = 0; i < 4; ++i) {
                bool gt = acc[i] > best[r][i];
                best[r][i] = gt ? acc[i] : best[r][i];
                bidx[r][i] = gt ? kt     : bidx[r][i];
            }
        }
    }

    // cross-lane argmax reduce over the 16 columns of each row, then atomic combine
    int colc = lane & 15;
    #pragma unroll
    for (int r = 0; r < 4; ++r) {
        #pragma unroll
        for (int i = 0; i < 4; ++i) {
            float s  = best[r][i];
            int   kg = kc * 256 + bidx[r][i] * 16 + colc;   // global codeword idx
            #pragma unroll
            for (int off = 1; off <= 8; off <<= 1) {
                float os  = __shfl_xor(s, off, 64);
                int   okg = __shfl_xor(kg, off, 64);
                bool take = (os > s) || (os == s && okg < kg);
                s  = take ? os  : s;
                kg = take ? okg : kg;
            }
            if (colc == 0) {
                int row = (rt0 + r) * 16 + (lane >> 4) * 4 + i;
                unsigned u    = __float_as_uint(s);
                unsigned mono = (u & 0x80000000u) ? ~u : (u | 0x80000000u);
                unsigned long long key =
                    ((unsigned long long)mono << 32) | (unsigned)(~(unsigned)kg);
                atomicMax(keys + row, key);
            }
        }
    }
}

__global__ __launch_bounds__(256) void decode_kernel(const unsigned long long* __restrict__ keys,
                                                     int* __restrict__ out) {
    int i = blockIdx.x * 256 + threadIdx.x;
    if (i < M_ROWS) out[i] = (int)(~(unsigned)(keys[i] & 0xFFFFFFFFull));
}

extern "C" void kernel_launch(void* const* d_in, const int* in_sizes, int n_in,
                              void* d_out, int out_size, void* d_ws, size_t ws_size,
                              hipStream_t stream) {
    const float* hs = (const float*)d_in[0];   // [8,2000,320]
    const float* P  = (const float*)d_in[1];   // [1,320,16]
    const float* CB = (const float*)d_in[2];   // [1,8192,16]
    int* out = (int*)d_out;                    // [8,1,2000] int32

    char* ws = (char*)d_ws;
    unsigned short* Xa  = (unsigned short*)(ws + XA_OFF);
    unsigned short* Xb  = (unsigned short*)(ws + XB_OFF);
    unsigned short* CBa = (unsigned short*)(ws + CBA_OFF);
    unsigned short* CBc = (unsigned short*)(ws + CBC_OFF);
    unsigned long long* keys = (unsigned long long*)(ws + KEYS_OFF);

    proj_pack<<<dim3(250), dim3(256), 0, stream>>>(hs, P, Xa, Xb);
    cb_pack<<<dim3(K_CB / 64), dim3(256), 0, stream>>>(CB, CBa, CBc);
    init_keys<<<dim3((16 * N_RT_PAD) / 256), dim3(256), 0, stream>>>(keys);
    score_kernel<<<dim3(63, NCHUNK), dim3(256), 0, stream>>>(Xa, Xb, CBa, CBc, keys);
    decode_kernel<<<dim3(63), dim3(256), 0, stream>>>(keys, out);
}

// Round 4
// 64.515 us; speedup vs baseline: 1.7540x; 1.7540x over previous
//
#include <hip/hip_runtime.h>
#include <stdint.h>

// Problem constants
#define M_ROWS   16000        // B*T
#define N_RT     1000         // real 16-row tiles (16000/16 exactly)
#define N_RT_PAD 1008         // padded: 42 row-blocks x 24 tiles
#define D_IN     320
#define E_DIM    16
#define K_CB     8192
#define NCHUNK   32           // k-chunks (16 k-tiles each)
#define KT_PER_CHUNK 16
#define RPT      6            // row-tiles per wave

typedef __attribute__((ext_vector_type(8))) short bf16x8;
typedef __attribute__((ext_vector_type(4))) float f32x4;

// Workspace layout (bytes) — same as round 2
#define XA_OFF   0u                       // [1008 tiles][64 lanes][8 bf16]  (h|m)
#define XB_OFF   1032192u                 // same shape                       (l|h)
#define CBA_OFF  2064384u                 // [512 ktiles][64 lanes][8 bf16]  (h'|m')
#define CBC_OFF  2588672u                 // same                             (h'|l')
#define KEYS_OFF 3112960u                 // [16128] u64

__device__ __forceinline__ unsigned short f2bf(float x) {
    union { float f; unsigned u; } v; v.f = x;
    unsigned r = v.u + 0x7FFFu + ((v.u >> 16) & 1u);   // round-to-nearest-even
    return (unsigned short)(r >> 16);
}
__device__ __forceinline__ float bf2f(unsigned short b) {
    union { unsigned u; float f; } v; v.u = ((unsigned)b) << 16; return v.f;
}

// ---------- Projection + exact 3-way bf16 split + A-fragment packing ----------
__global__ __launch_bounds__(256) void proj_pack(const float* __restrict__ hs,
                                                 const float* __restrict__ P,
                                                 unsigned short* __restrict__ Xa,
                                                 unsigned short* __restrict__ Xb) {
    int t   = threadIdx.x;
    int row = blockIdx.x * 64 + (t >> 2);
    int eq  = t & 3;
    if (row >= M_ROWS) return;
    const float* hrow = hs + (size_t)row * D_IN;
    float ax = 0.f, ay = 0.f, az = 0.f, aw = 0.f;
    #pragma unroll 4
    for (int d = 0; d < D_IN; d += 4) {
        float4 h4 = *reinterpret_cast<const float4*>(hrow + d);
        float4 p0 = *reinterpret_cast<const float4*>(P + (size_t)(d + 0) * E_DIM + eq * 4);
        float4 p1 = *reinterpret_cast<const float4*>(P + (size_t)(d + 1) * E_DIM + eq * 4);
        float4 p2 = *reinterpret_cast<const float4*>(P + (size_t)(d + 2) * E_DIM + eq * 4);
        float4 p3 = *reinterpret_cast<const float4*>(P + (size_t)(d + 3) * E_DIM + eq * 4);
        ax += h4.x * p0.x + h4.y * p1.x + h4.z * p2.x + h4.w * p3.x;
        ay += h4.x * p0.y + h4.y * p1.y + h4.z * p2.y + h4.w * p3.y;
        az += h4.x * p0.z + h4.y * p1.z + h4.z * p2.z + h4.w * p3.z;
        aw += h4.x * p0.w + h4.y * p1.w + h4.z * p2.w + h4.w * p3.w;
    }
    float v[4] = {ax, ay, az, aw};
    ushort4 h, m, l;
    unsigned short* hp = (unsigned short*)&h;
    unsigned short* mp = (unsigned short*)&m;
    unsigned short* lp = (unsigned short*)&l;
    #pragma unroll
    for (int i = 0; i < 4; ++i) {
        unsigned short hb = f2bf(v[i]);      float r1 = v[i] - bf2f(hb);
        unsigned short mb = f2bf(r1);        float r2 = r1 - bf2f(mb);
        unsigned short lb = f2bf(r2);        // exact: v = h + m + l
        hp[i] = hb; mp[i] = mb; lp[i] = lb;
    }
    int rt = row >> 4, rl = row & 15;
    int g  = eq >> 1;
    int j0 = (eq & 1) * 4;
    size_t base = (size_t)rt * 512;
    *reinterpret_cast<ushort4*>(Xa + base + ((g    ) * 16 + rl) * 8 + j0) = h;
    *reinterpret_cast<ushort4*>(Xa + base + ((2 + g) * 16 + rl) * 8 + j0) = m;
    *reinterpret_cast<ushort4*>(Xb + base + ((g    ) * 16 + rl) * 8 + j0) = l;
    *reinterpret_cast<ushort4*>(Xb + base + ((2 + g) * 16 + rl) * 8 + j0) = h;
}

// ---------- Codebook split + B-fragment packing + keys init (fused) ----------
__global__ __launch_bounds__(256) void cb_pack(const float* __restrict__ CB,
                                               unsigned short* __restrict__ CBa,
                                               unsigned short* __restrict__ CBc,
                                               unsigned long long* __restrict__ keys) {
    int t   = threadIdx.x;
    int gid = blockIdx.x * 256 + t;
    if (gid < 16 * N_RT_PAD) keys[gid] = 0ull;   // fused init_keys
    int c  = blockIdx.x * 64 + (t >> 2);
    int eq = t & 3;
    float4 v4 = *reinterpret_cast<const float4*>(CB + (size_t)c * E_DIM + eq * 4);
    float v[4] = {v4.x, v4.y, v4.z, v4.w};
    ushort4 h, m, l;
    unsigned short* hp = (unsigned short*)&h;
    unsigned short* mp = (unsigned short*)&m;
    unsigned short* lp = (unsigned short*)&l;
    #pragma unroll
    for (int i = 0; i < 4; ++i) {
        unsigned short hb = f2bf(v[i]);      float r1 = v[i] - bf2f(hb);
        unsigned short mb = f2bf(r1);        float r2 = r1 - bf2f(mb);
        unsigned short lb = f2bf(r2);
        hp[i] = hb; mp[i] = mb; lp[i] = lb;
    }
    int kt = c >> 4, cl = c & 15;
    int g  = eq >> 1;
    int j0 = (eq & 1) * 4;
    size_t base = (size_t)kt * 512;
    *reinterpret_cast<ushort4*>(CBa + base + ((g    ) * 16 + cl) * 8 + j0) = h;
    *reinterpret_cast<ushort4*>(CBa + base + ((2 + g) * 16 + cl) * 8 + j0) = m;
    *reinterpret_cast<ushort4*>(CBc + base + ((g    ) * 16 + cl) * 8 + j0) = h;
    *reinterpret_cast<ushort4*>(CBc + base + ((2 + g) * 16 + cl) * 8 + j0) = l;
}

// ---------- MFMA score + fused argmax ----------
// grid (42 row-blocks, 32 k-chunks) x 256 threads (4 waves).
// Wave owns 6 row-tiles (96 rows). Depth-1 prefetch of the 3 B-fragment
// streams with register rotation; 3 chained MFMAs per (rt,kt) give full
// fp32-precision scores; u64-packed-key shfl reduce; one atomicMax per row.
__global__ __launch_bounds__(256, 3) void score_kernel(const unsigned short* __restrict__ Xa,
                                                       const unsigned short* __restrict__ Xb,
                                                       const unsigned short* __restrict__ CBa,
                                                       const unsigned short* __restrict__ CBc,
                                                       unsigned long long* __restrict__ keys) {
    int t    = threadIdx.x;
    int lane = t & 63;
    int w    = t >> 6;
    int rb   = blockIdx.x;    // 0..41
    int kc   = blockIdx.y;    // 0..31
    int rt0  = rb * 24 + w * RPT;

    bf16x8 a_hm[RPT], a_lh[RPT];
    #pragma unroll
    for (int r = 0; r < RPT; ++r) {
        a_hm[r] = *reinterpret_cast<const bf16x8*>(Xa + ((size_t)(rt0 + r) * 64 + lane) * 8);
        a_lh[r] = *reinterpret_cast<const bf16x8*>(Xb + ((size_t)(rt0 + r) * 64 + lane) * 8);
    }
    float best[RPT][4];
    int   bidx[RPT][4];
    #pragma unroll
    for (int r = 0; r < RPT; ++r)
        #pragma unroll
        for (int i = 0; i < 4; ++i) { best[r][i] = -3.0e38f; bidx[r][i] = 0; }

    const bf16x8* gb1 = reinterpret_cast<const bf16x8*>(CBa + (size_t)kc * KT_PER_CHUNK * 512);
    const bf16x8* gb3 = reinterpret_cast<const bf16x8*>(CBc + (size_t)kc * KT_PER_CHUNK * 512);
    int lsw = lane ^ 32;      // swapped-half lane for the [m'|h'] operand

    bf16x8 c1 = gb1[lane];
    bf16x8 c2 = gb1[lsw];
    bf16x8 c3 = gb3[lane];

    #pragma unroll 2
    for (int kt = 0; kt < KT_PER_CHUNK; ++kt) {
        // depth-1 prefetch (kt==15 reads 1KB past the chunk — still inside ws)
        bf16x8 n1 = gb1[(kt + 1) * 64 + lane];
        bf16x8 n2 = gb1[(kt + 1) * 64 + lsw];
        bf16x8 n3 = gb3[(kt + 1) * 64 + lane];
        #pragma unroll
        for (int r = 0; r < RPT; ++r) {
            f32x4 acc = {0.f, 0.f, 0.f, 0.f};
            acc = __builtin_amdgcn_mfma_f32_16x16x32_bf16(a_hm[r], c1, acc, 0, 0, 0); // hh+mm
            acc = __builtin_amdgcn_mfma_f32_16x16x32_bf16(a_hm[r], c2, acc, 0, 0, 0); // hm+mh
            acc = __builtin_amdgcn_mfma_f32_16x16x32_bf16(a_lh[r], c3, acc, 0, 0, 0); // lh+hl
            #pragma unroll
            for (int i = 0; i < 4; ++i) {
                bool gt = acc[i] > best[r][i];
                best[r][i] = gt ? acc[i] : best[r][i];
                bidx[r][i] = gt ? kt     : bidx[r][i];
            }
        }
        c1 = n1; c2 = n2; c3 = n3;
    }

    // Pack (score, idx) into u64 key once, 4-round 16-lane max reduce, 1 atomic/row.
    // Key = mono(score)<<32 | ~idx : max => higher score, then lower index on ties
    // (bitwise-identical semantics to the verified round-2 path).
    int colc = lane & 15;
    #pragma unroll
    for (int r = 0; r < RPT; ++r) {
        #pragma unroll
        for (int i = 0; i < 4; ++i) {
            unsigned u    = __float_as_uint(best[r][i]);
            unsigned mono = (u & 0x80000000u) ? ~u : (u | 0x80000000u);
            unsigned kg   = (unsigned)(kc * 256 + bidx[r][i] * 16 + colc);
            unsigned long long key = ((unsigned long long)mono << 32) | (unsigned)(~kg);
            #pragma unroll
            for (int off = 1; off <= 8; off <<= 1) {
                unsigned long long ok =
                    (((unsigned long long)(unsigned)__shfl_xor((int)(key >> 32), off, 64)) << 32) |
                    (unsigned)__shfl_xor((int)(unsigned)key, off, 64);
                key = (ok > key) ? ok : key;
            }
            if (colc == 0) {
                int row = (rt0 + r) * 16 + (lane >> 4) * 4 + i;
                if (row < M_ROWS) atomicMax(keys + row, key);
            }
        }
    }
}

__global__ __launch_bounds__(256) void decode_kernel(const unsigned long long* __restrict__ keys,
                                                     int* __restrict__ out) {
    int i = blockIdx.x * 256 + threadIdx.x;
    if (i < M_ROWS) out[i] = (int)(~(unsigned)(keys[i] & 0xFFFFFFFFull));
}

extern "C" void kernel_launch(void* const* d_in, const int* in_sizes, int n_in,
                              void* d_out, int out_size, void* d_ws, size_t ws_size,
                              hipStream_t stream) {
    const float* hs = (const float*)d_in[0];   // [8,2000,320]
    const float* P  = (const float*)d_in[1];   // [1,320,16]
    const float* CB = (const float*)d_in[2];   // [1,8192,16]
    int* out = (int*)d_out;                    // [8,1,2000] int32

    char* ws = (char*)d_ws;
    unsigned short* Xa  = (unsigned short*)(ws + XA_OFF);
    unsigned short* Xb  = (unsigned short*)(ws + XB_OFF);
    unsigned short* CBa = (unsigned short*)(ws + CBA_OFF);
    unsigned short* CBc = (unsigned short*)(ws + CBC_OFF);
    unsigned long long* keys = (unsigned long long*)(ws + KEYS_OFF);

    proj_pack<<<dim3(250), dim3(256), 0, stream>>>(hs, P, Xa, Xb);
    cb_pack<<<dim3(K_CB / 64), dim3(256), 0, stream>>>(CB, CBa, CBc, keys);
    score_kernel<<<dim3(42, NCHUNK), dim3(256), 0, stream>>>(Xa, Xb, CBa, CBc, keys);
    decode_kernel<<<dim3(63), dim3(256), 0, stream>>>(keys, out);
}